// Round 14
// baseline (324.317 us; speedup 1.0000x reference)
//
#include <hip/hip_runtime.h>
#include <math.h>

#define BS   64
#define CH   256
#define NPIX 3136        // 56*56
#define NK   3
#define TILE 256         // pixels per block tile
#define NT   13          // ceil(3136/256); last tile = 64 px

// ws layout (floats): sa then qx
#define WS_SA 0
#define WS_QX (BS*NK)

typedef float f32x4 __attribute__((ext_vector_type(4)));

// ---------------------------------------------------------------------------
// Contiguous-read fused kernel.
// Phase A: wave w owns channels [64w, 64w+64); for each channel the wave's 64
//   lanes load 64 x float4 = 1024 B CONTIGUOUS (fixes the 256B-scatter DRAM
//   pattern that pinned all prior variants at ~1.7 TB/s). Lane l accumulates
//   center-dots for pixels 4l..4l+3. Cross-wave combine via slot-major LDS.
// Softmax: all 256 threads, one pixel each.
// Phase B: lane-owns-channel; thread c streams its 1 KB channel row (L3-hot,
//   sequential), assign via wave-uniform LDS broadcast; no shuffles; 3 atomics.
// ---------------------------------------------------------------------------
__global__ __launch_bounds__(256)
void pgn_main(const float* __restrict__ x,        // [BS][CH][NPIX]
              const float* __restrict__ centers,  // [NK][CH]
              const float* __restrict__ psf,      // [NK]
              float* __restrict__ assign_out,     // [BS][NK][NPIX]
              float* __restrict__ sa,             // [BS][NK]      (zeroed)
              float* __restrict__ qx)             // [BS][NK][CH]  (zeroed)
{
    __shared__ float4 ctr_sh[CH];          // 4 KB   {c0,c1,c2,0} per channel
    __shared__ float  part[16*4*64];       // 16 KB  [slot16][wave4][quad64]
    __shared__ float  a_sh[NK][TILE];      // 3 KB
    __shared__ float  cred[4][NK];
    __shared__ float  csq_sh[NK];
    __shared__ float  sred[4][NK];

    const int tid  = threadIdx.x;
    const int b    = blockIdx.x / NT;
    const int t    = blockIdx.x % NT;
    const int n0   = t * TILE;
    const int tlen = (NPIX - n0 < TILE) ? (NPIX - n0) : TILE;   // 256 or 64
    const int w    = tid >> 6;
    const int lane = tid & 63;

    // ---- centers transpose + c_sq ----
    {
        const float c0 = centers[tid], c1 = centers[CH + tid], c2 = centers[2*CH + tid];
        ctr_sh[tid] = make_float4(c0, c1, c2, 0.f);
        float s0 = c0*c0, s1 = c1*c1, s2 = c2*c2;
        #pragma unroll
        for (int m = 32; m; m >>= 1) {
            s0 += __shfl_xor(s0, m, 64);
            s1 += __shfl_xor(s1, m, 64);
            s2 += __shfl_xor(s2, m, 64);
        }
        if (lane == 0) { cred[w][0] = s0; cred[w][1] = s1; cred[w][2] = s2; }
    }
    __syncthreads();
    if (tid < NK) csq_sh[tid] = cred[0][tid] + cred[1][tid] + cred[2][tid] + cred[3][tid];

    // ---- Phase A: wave reads its 64 channel rows, 1 KB contiguous each ----
    float cxa[NK][4], xsq[4];
    #pragma unroll
    for (int j = 0; j < 4; ++j) { cxa[0][j]=0.f; cxa[1][j]=0.f; cxa[2][j]=0.f; xsq[j]=0.f; }

    const int c0g = w * 64;                       // this wave's channel base
    const bool lv = (4*lane) < tlen;              // lane has valid pixels?
    // invalid lanes read tile start (in-bounds); their results are never used
    const float* xrow = x + (size_t)b * CH * NPIX + n0 + (lv ? 4*lane : 0);

    #pragma unroll 2
    for (int cu = 0; cu < 64; cu += 8) {
        f32x4 xv8[8];
        #pragma unroll
        for (int u = 0; u < 8; ++u)
            xv8[u] = *(const f32x4*)(xrow + (size_t)(c0g + cu + u) * NPIX);
        #pragma unroll
        for (int u = 0; u < 8; ++u) {
            const float4 cv = ctr_sh[c0g + cu + u];
            #pragma unroll
            for (int j = 0; j < 4; ++j) {
                const float xj = xv8[u][j];
                cxa[0][j] = fmaf(cv.x, xj, cxa[0][j]);
                cxa[1][j] = fmaf(cv.y, xj, cxa[1][j]);
                cxa[2][j] = fmaf(cv.z, xj, cxa[2][j]);
                xsq[j]    = fmaf(xj, xj, xsq[j]);
            }
        }
    }

    // slot-major store: conflict-free scalar writes (lanes -> consecutive addrs)
    #pragma unroll
    for (int k = 0; k < NK; ++k)
        #pragma unroll
        for (int j = 0; j < 4; ++j)
            part[(k*4 + j)*256 + w*64 + lane] = cxa[k][j];
    #pragma unroll
    for (int j = 0; j < 4; ++j)
        part[(12 + j)*256 + w*64 + lane] = xsq[j];
    __syncthreads();   // part, csq_sh ready

    // ---- softmax: one pixel per thread ----
    float a0 = 0.f, a1 = 0.f, a2 = 0.f;
    {
        const int p = tid, q = p >> 2, r = p & 3;
        if (p < tlen) {
            float cx0 = 0.f, cx1 = 0.f, cx2 = 0.f, xs = 0.f;
            #pragma unroll
            for (int ww = 0; ww < 4; ++ww) {
                cx0 += part[(0  + r)*256 + ww*64 + q];
                cx1 += part[(4  + r)*256 + ww*64 + q];
                cx2 += part[(8  + r)*256 + ww*64 + q];
                xs  += part[(12 + r)*256 + ww*64 + q];
            }
            const float rb0 = 1.f + __expf(-psf[0]);
            const float rb1 = 1.f + __expf(-psf[1]);
            const float rb2 = 1.f + __expf(-psf[2]);
            const float l0 = fminf(2.f*cx0 - xs - csq_sh[0], 0.f) * rb0;
            const float l1 = fminf(2.f*cx1 - xs - csq_sh[1], 0.f) * rb1;
            const float l2 = fminf(2.f*cx2 - xs - csq_sh[2], 0.f) * rb2;
            const float m  = fmaxf(l0, fmaxf(l1, l2));
            const float e0 = __expf(l0 - m), e1 = __expf(l1 - m), e2 = __expf(l2 - m);
            const float inv = 1.f / (e0 + e1 + e2);
            a0 = e0*inv; a1 = e1*inv; a2 = e2*inv;

            float* ao = assign_out + (size_t)b * NK * NPIX + n0 + p;
            __builtin_nontemporal_store(a0, ao);
            __builtin_nontemporal_store(a1, ao + NPIX);
            __builtin_nontemporal_store(a2, ao + 2*NPIX);
        }
        a_sh[0][p] = a0; a_sh[1][p] = a1; a_sh[2][p] = a2;

        // block-level sum of assignments
        float s0 = a0, s1 = a1, s2 = a2;
        #pragma unroll
        for (int m2 = 32; m2; m2 >>= 1) {
            s0 += __shfl_xor(s0, m2, 64);
            s1 += __shfl_xor(s1, m2, 64);
            s2 += __shfl_xor(s2, m2, 64);
        }
        if (lane == 0) { sred[w][0] = s0; sred[w][1] = s1; sred[w][2] = s2; }
    }
    __syncthreads();   // a_sh, sred ready
    if (tid < NK)
        atomicAdd(&sa[b*NK + tid], sred[0][tid] + sred[1][tid] + sred[2][tid] + sred[3][tid]);

    // ---- Phase B: lane-owns-channel pooling (sequential L3-hot reads) ----
    {
        const float* xc = x + ((size_t)b * CH + tid) * NPIX + n0;
        float q0 = 0.f, q1 = 0.f, q2 = 0.f;
        #pragma unroll 4
        for (int j = 0; j < tlen; j += 4) {
            const f32x4  v  = *(const f32x4*)(xc + j);
            const float4 A0 = *(const float4*)&a_sh[0][j];   // wave-uniform: broadcast
            const float4 A1 = *(const float4*)&a_sh[1][j];
            const float4 A2 = *(const float4*)&a_sh[2][j];
            q0 = fmaf(A0.x, v.x, fmaf(A0.y, v.y, fmaf(A0.z, v.z, fmaf(A0.w, v.w, q0))));
            q1 = fmaf(A1.x, v.x, fmaf(A1.y, v.y, fmaf(A1.z, v.z, fmaf(A1.w, v.w, q1))));
            q2 = fmaf(A2.x, v.x, fmaf(A2.y, v.y, fmaf(A2.z, v.z, fmaf(A2.w, v.w, q2))));
        }
        float* qb = qx + (size_t)b * NK * CH + tid;
        atomicAdd(qb,        q0);
        atomicAdd(qb + CH,   q1);
        atomicAdd(qb + 2*CH, q2);
    }
}

// ---------------------------------------------------------------------------
// Finalize: qx/sum_ass, subtract centers, /sigma, L2-normalize over channels,
// transposed store to outputs[b][c][k].
// ---------------------------------------------------------------------------
__global__ __launch_bounds__(256)
void pgn_final(const float* __restrict__ qx,       // [BS][NK][CH]
               const float* __restrict__ sa,       // [BS][NK]
               const float* __restrict__ centers,  // [NK][CH]
               const float* __restrict__ psf,      // [NK]
               float* __restrict__ out)            // [BS][CH][NK]
{
    const int b = blockIdx.x;
    const int c = threadIdx.x;
    const int wave = c >> 6, lane = c & 63;
    __shared__ float red[4][NK];
    __shared__ float nrm[NK];

    float v[NK], ss[NK];
    #pragma unroll
    for (int k = 0; k < NK; ++k) {
        const float beta = 1.f / (1.f + __expf(-psf[k]));
        const float sig  = sqrtf(0.5f * beta);
        const float s    = fmaxf(sa[b*NK + k], 1e-5f);
        const float q    = qx[((size_t)b*NK + k)*CH + c] / s;
        v[k]  = (q - centers[k*CH + c]) / sig;
        ss[k] = v[k] * v[k];
    }
    #pragma unroll
    for (int m = 32; m; m >>= 1) {
        ss[0] += __shfl_xor(ss[0], m, 64);
        ss[1] += __shfl_xor(ss[1], m, 64);
        ss[2] += __shfl_xor(ss[2], m, 64);
    }
    if (lane == 0) { red[wave][0] = ss[0]; red[wave][1] = ss[1]; red[wave][2] = ss[2]; }
    __syncthreads();
    if (c < NK) {
        const float tot = red[0][c] + red[1][c] + red[2][c] + red[3][c];
        nrm[c] = fmaxf(sqrtf(tot), 1e-12f);
    }
    __syncthreads();
    float* o = out + ((size_t)b*CH + c)*NK;
    #pragma unroll
    for (int k = 0; k < NK; ++k) o[k] = v[k] / nrm[k];
}

// ---------------------------------------------------------------------------
extern "C" void kernel_launch(void* const* d_in, const int* in_sizes, int n_in,
                              void* d_out, int out_size, void* d_ws, size_t ws_size,
                              hipStream_t stream)
{
    const float* feat    = (const float*)d_in[0];
    const float* centers = (const float*)d_in[1];
    const float* psf     = (const float*)d_in[2];

    float* out        = (float*)d_out;            // [BS][CH][NK] first
    float* assign_out = out + (size_t)BS*CH*NK;   // then [BS][NK][NPIX]

    float* sa = (float*)d_ws + WS_SA;             // [BS][NK]
    float* qx = (float*)d_ws + WS_QX;             // [BS][NK][CH]

    // zero the atomic accumulators (ws is poisoned 0xAA before every launch)
    (void)hipMemsetAsync(d_ws, 0, (BS*NK + BS*NK*CH) * sizeof(float), stream);

    pgn_main<<<dim3(BS*NT), dim3(256), 0, stream>>>(
        feat, centers, psf, assign_out, sa, qx);

    pgn_final<<<dim3(BS), dim3(256), 0, stream>>>(qx, sa, centers, psf, out);
}